// Round 5
// baseline (16592.857 us; speedup 1.0000x reference)
//
#include <hip/hip_runtime.h>

typedef unsigned short u16;
typedef unsigned int u32;
typedef unsigned long long u64;
typedef float f32x2 __attribute__((ext_vector_type(2)));

#define BATCH 256
#define TT 512
#define HID 256
#define GATES 1024   // 4*HID
#define NEMB 512
#define VOC 27
#define HPAD 260     // 1040B row: 16B aligned, 2-way LDS conflict max (free)

__device__ __forceinline__ float bf1(u16 x){ union{u32 u; float f;} v; v.u = ((u32)x) << 16; return v.f; }
__device__ __forceinline__ u16 f2bf(float f){
  union{float f; u32 u;} v; v.f = f;
  u32 u = v.u;
  return (u16)((u + 0x7fffu + ((u >> 16) & 1u)) >> 16);
}
__device__ __forceinline__ float sigm(float x){ return 1.f / (1.f + __expf(-x)); }
__device__ __forceinline__ f32x2 lo2(float4 v){ f32x2 r; r.x = v.x; r.y = v.y; return r; }
__device__ __forceinline__ f32x2 hi2(float4 v){ f32x2 r; r.x = v.z; r.y = v.w; return r; }

// Sniff storage dtype of b_ih0 (1024 elems, |v| <= 1/16).
__global__ void k_detect(const u16* __restrict__ b, int* __restrict__ flag) {
  int bad = 0;
  for (int k = threadIdx.x; k < 512; k += 64)
    if (((b[2 * k] >> 7) & 0xFF) >= 127) bad = 1;
  unsigned long long m = __ballot(bad);   // single wave
  if (threadIdx.x == 0) flag[0] = (m != 0ULL) ? 0 : 1;
}

__global__ void k_convert(const void* __restrict__ src, float* __restrict__ dst,
                          int n, const int* __restrict__ flag) {
  int i = blockIdx.x * 256 + threadIdx.x;
  if (i >= n) return;
  dst[i] = flag[0] ? bf1(((const u16*)src)[i]) : ((const float*)src)[i];
}

// W0emb[v][g] = sum_i emb[v][i]*w_ih0[g][i] + b_ih0[g] + b_hh0[g]; emb row 26 := 0
__global__ void k_prep(const void* __restrict__ emb, const void* __restrict__ wih,
                       const void* __restrict__ bih, const void* __restrict__ bhh,
                       const int* __restrict__ flag, float* __restrict__ W0) {
  int idx = blockIdx.x * 256 + threadIdx.x;
  if (idx >= VOC * GATES) return;
  int v = idx >> 10, g = idx & (GATES - 1);
  int isbf = flag[0];
  float acc = isbf ? (bf1(((const u16*)bih)[g]) + bf1(((const u16*)bhh)[g]))
                   : (((const float*)bih)[g] + ((const float*)bhh)[g]);
  if (v != 26) {
    float s = 0.f;
    if (isbf) {
      const u16* e = (const u16*)emb + v * NEMB;
      const u16* w = (const u16*)wih + g * NEMB;
      for (int i = 0; i < NEMB; i++) s = fmaf(bf1(e[i]), bf1(w[i]), s);
    } else {
      const float* e = (const float*)emb + v * NEMB;
      const float* w = (const float*)wih + g * NEMB;
      for (int i = 0; i < NEMB; i++) s = fmaf(e[i], w[i], s);
    }
    acc += s;
  }
  W0[idx] = acc;
}

// Persistent fused 2-layer LSTM, 256 blocks x 1024 threads, 1 block/CU.
// Thread (tb = tid&15, ks = (tid>>4)&3, j16 = tid>>6):
//   owns the 4 gate rows of j = jc*16+j16 over K-slice [ks*64, ks*64+64).
//   -> each staged LDS float4 reused 4x (gates share h); partial sums reduced
//      in-register via __shfl_xor(16/32) butterfly (ks lives in lane bits 4-5).
// Exchange: per-block FLAG slots (64B apart, plain relaxed-agent stores -> no
// contended RMW). Wave roles after gemm barrier: wave0 = L0 pointwise + publish,
// wave1 = L1 pointwise + publish, wave2 = poll peers' flags for next iter.
// Ordering: publisher drains its own h stores (s_waitcnt vmcnt(0)) before the
// flag store; stores/loads are relaxed AGENT scope (coherence point, no L2
// dirty lines, no wbl2/inv) — protocol proven R2-R4.
__global__ __launch_bounds__(1024) void k_lstm(
    const int* __restrict__ ids, const float* __restrict__ W0,
    const float* __restrict__ whh0, const float* __restrict__ wih1,
    const float* __restrict__ whh1,
    const float* __restrict__ bih1, const float* __restrict__ bhh1,
    float* __restrict__ h0a, float* __restrict__ h0b,
    float* __restrict__ h1a, float* __restrict__ h1b,
    u32* __restrict__ bar)
{
  const int tid = threadIdx.x;
  const int bid = blockIdx.x;
  const int xcd = bid & 7, m = bid >> 3;
  const int bg = xcd * 2 + (m & 1);   // [0,16)
  const int jc = m >> 1;              // [0,16)

  const int tb  = tid & 15;           // batch within group
  const int ks  = (tid >> 4) & 3;     // K-slice [ks*64, ks*64+64)
  const int j16 = tid >> 6;           // j within chunk; == wave id
  const int wv  = tid >> 6;
  const int ln  = tid & 63;

  __shared__ __align__(16) float hp0[2][16][HPAD]; // h0[t-1]/h0[t-2] tiles
  __shared__ __align__(16) float hp1[16][HPAD];    // h1[t-3] tile
  __shared__ float gs0[64][17];       // layer0 gates [gate*16+j16][tb]
  __shared__ float gs1[64][17];       // layer1 gates
  __shared__ int   ids_l[16][TT + 1]; // all ids for this bg (padded rows)

  // per-thread row offsets for the 4 gates (same row structure in all 3 mats)
  int roff[4];
  #pragma unroll
  for (int g = 0; g < 4; ++g) roff[g] = (g * 256 + jc * 16 + j16) * HID + ks * 64;

  float bs[4];
  #pragma unroll
  for (int g = 0; g < 4; ++g) {
    int grow = g * 256 + jc * 16 + j16;
    bs[g] = bih1[grow] + bhh1[grow];
  }

  // pointwise c-state: wave0 holds layer0 (4 cells/lane), wave1 holds layer1
  float c0r[4] = {0.f, 0.f, 0.f, 0.f};
  float c1r[4] = {0.f, 0.f, 0.f, 0.f};

  // flag arrays: slot (bg*16+jc)*16 u32 (64B apart)
  u32* flags0 = bar;
  u32* flags1 = bar + 256 * 16;

  // preload all ids for this batch group (coalesced, once)
  #pragma unroll
  for (int u = 0; u < 8; ++u) {
    int e = tid + 1024 * u;           // [0, 8192)
    int b = e >> 9, t2 = e & 511;
    ids_l[b][t2] = ids[(bg * 16 + b) * TT + t2];
  }

  for (int t = 0; t <= TT + 1; ++t) {
    // ---- wave2: poll peers' flags (parallel lanes, no RMW) ----
    if (wv == 2) {
      u32 need0 = (t >= 1 && t <= TT) ? (u32)t : 0u;
      u32 need1 = (t >= 3) ? (u32)(t - 2) : 0u;
      const u32* fp = nullptr;
      u32 need = 0;
      if (ln < 16)      { fp = flags0 + (bg * 16 + ln) * 16;        need = need0; }
      else if (ln < 32) { fp = flags1 + (bg * 16 + (ln - 16)) * 16; need = need1; }
      if (need) {
        for (;;) {
          bool ok = true;
          if (fp) ok = __hip_atomic_load(fp, __ATOMIC_RELAXED, __HIP_MEMORY_SCOPE_AGENT) >= need;
          if (__all(ok)) break;
          __builtin_amdgcn_s_sleep(2);
        }
      }
    }
    __syncthreads();   // A: flags ok + prev-iter gemm done reading hp tiles

    // ---- stage tiles (relaxed agent loads; coalesced) ----
    if (t <= TT) {
      const float* h0p = ((t + 1) & 1) ? h0b : h0a;      // h0[t-1]
      const u64* s0 = (const u64*)(h0p + bg * 16 * HID);
      float (*dst)[HPAD] = hp0[t & 1];
      #pragma unroll
      for (int u = 0; u < 2; ++u) {
        int e = tid + 1024 * u;
        u64 v = __hip_atomic_load(s0 + e, __ATOMIC_RELAXED, __HIP_MEMORY_SCOPE_AGENT);
        *(u64*)&dst[e >> 7][(e & 127) * 2] = v;
      }
    }
    if (t >= 2) {
      const float* h1p = ((t + 1) & 1) ? h1b : h1a;      // h1[t-3]
      const u64* s1 = (const u64*)(h1p + bg * 16 * HID);
      #pragma unroll
      for (int u = 0; u < 2; ++u) {
        int e = tid + 1024 * u;
        u64 v = __hip_atomic_load(s1 + e, __ATOMIC_RELAXED, __HIP_MEMORY_SCOPE_AGENT);
        *(u64*)&hp1[e >> 7][(e & 127) * 2] = v;
      }
    }
    __syncthreads();   // B: tiles staged

    // ---- layer0 gemm, step t: 4 gate-rows x K-slice 64 per thread ----
    if (t < TT) {
      float xg0 = 0.f, xg1 = 0.f, xg2 = 0.f, xg3 = 0.f;
      if ((tid & 48) == 0) {          // ks==0 lanes add x-gate + write result
        const float* xr = W0 + (size_t)ids_l[tb][t] * GATES + jc * 16 + j16;
        xg0 = xr[0]; xg1 = xr[256]; xg2 = xr[512]; xg3 = xr[768];
      }
      const float4* h4 = (const float4*)&hp0[t & 1][tb][ks * 64];
      const float4* w0 = (const float4*)(whh0 + roff[0]);
      const float4* w1 = (const float4*)(whh0 + roff[1]);
      const float4* w2 = (const float4*)(whh0 + roff[2]);
      const float4* w3 = (const float4*)(whh0 + roff[3]);
      f32x2 aL0={0,0}, aH0={0,0}, aL1={0,0}, aH1={0,0};
      f32x2 aL2={0,0}, aH2={0,0}, aL3={0,0}, aH3={0,0};
      #pragma unroll 4
      for (int k = 0; k < 16; ++k) {
        float4 hv = h4[k];
        float4 q0 = w0[k], q1 = w1[k], q2 = w2[k], q3 = w3[k];
        aL0 = lo2(q0) * lo2(hv) + aL0; aH0 = hi2(q0) * hi2(hv) + aH0;
        aL1 = lo2(q1) * lo2(hv) + aL1; aH1 = hi2(q1) * hi2(hv) + aH1;
        aL2 = lo2(q2) * lo2(hv) + aL2; aH2 = hi2(q2) * hi2(hv) + aH2;
        aL3 = lo2(q3) * lo2(hv) + aL3; aH3 = hi2(q3) * hi2(hv) + aH3;
      }
      float s0 = aL0.x + aL0.y + aH0.x + aH0.y;
      float s1 = aL1.x + aL1.y + aH1.x + aH1.y;
      float s2 = aL2.x + aL2.y + aH2.x + aH2.y;
      float s3 = aL3.x + aL3.y + aH3.x + aH3.y;
      s0 += __shfl_xor(s0, 16); s0 += __shfl_xor(s0, 32);
      s1 += __shfl_xor(s1, 16); s1 += __shfl_xor(s1, 32);
      s2 += __shfl_xor(s2, 16); s2 += __shfl_xor(s2, 32);
      s3 += __shfl_xor(s3, 16); s3 += __shfl_xor(s3, 32);
      if ((tid & 48) == 0) {
        gs0[ 0 + j16][tb] = s0 + xg0;
        gs0[16 + j16][tb] = s1 + xg1;
        gs0[32 + j16][tb] = s2 + xg2;
        gs0[48 + j16][tb] = s3 + xg3;
      }
    }

    // ---- layer1 gemm, step t-2: 4 gate-rows x (64 of x + 64 of h) ----
    if (t >= 2) {
      const float4* x4 = (const float4*)&hp0[(t - 1) & 1][tb][ks * 64];
      const float4* h4 = (const float4*)&hp1[tb][ks * 64];
      const float4* wi0 = (const float4*)(wih1 + roff[0]);
      const float4* wi1 = (const float4*)(wih1 + roff[1]);
      const float4* wi2 = (const float4*)(wih1 + roff[2]);
      const float4* wi3 = (const float4*)(wih1 + roff[3]);
      const float4* wh0 = (const float4*)(whh1 + roff[0]);
      const float4* wh1 = (const float4*)(whh1 + roff[1]);
      const float4* wh2 = (const float4*)(whh1 + roff[2]);
      const float4* wh3 = (const float4*)(whh1 + roff[3]);
      f32x2 aL0={0,0}, aH0={0,0}, aL1={0,0}, aH1={0,0};
      f32x2 aL2={0,0}, aH2={0,0}, aL3={0,0}, aH3={0,0};
      #pragma unroll 2
      for (int k = 0; k < 16; ++k) {
        float4 xv = x4[k], hv = h4[k];
        float4 qi0 = wi0[k], qi1 = wi1[k], qi2 = wi2[k], qi3 = wi3[k];
        aL0 = lo2(qi0) * lo2(xv) + aL0; aH0 = hi2(qi0) * hi2(xv) + aH0;
        aL1 = lo2(qi1) * lo2(xv) + aL1; aH1 = hi2(qi1) * hi2(xv) + aH1;
        aL2 = lo2(qi2) * lo2(xv) + aL2; aH2 = hi2(qi2) * hi2(xv) + aH2;
        aL3 = lo2(qi3) * lo2(xv) + aL3; aH3 = hi2(qi3) * hi2(xv) + aH3;
        float4 qh0 = wh0[k], qh1 = wh1[k], qh2 = wh2[k], qh3 = wh3[k];
        aL0 = lo2(qh0) * lo2(hv) + aL0; aH0 = hi2(qh0) * hi2(hv) + aH0;
        aL1 = lo2(qh1) * lo2(hv) + aL1; aH1 = hi2(qh1) * hi2(hv) + aH1;
        aL2 = lo2(qh2) * lo2(hv) + aL2; aH2 = hi2(qh2) * hi2(hv) + aH2;
        aL3 = lo2(qh3) * lo2(hv) + aL3; aH3 = hi2(qh3) * hi2(hv) + aH3;
      }
      float s0 = aL0.x + aL0.y + aH0.x + aH0.y;
      float s1 = aL1.x + aL1.y + aH1.x + aH1.y;
      float s2 = aL2.x + aL2.y + aH2.x + aH2.y;
      float s3 = aL3.x + aL3.y + aH3.x + aH3.y;
      s0 += __shfl_xor(s0, 16); s0 += __shfl_xor(s0, 32);
      s1 += __shfl_xor(s1, 16); s1 += __shfl_xor(s1, 32);
      s2 += __shfl_xor(s2, 16); s2 += __shfl_xor(s2, 32);
      s3 += __shfl_xor(s3, 16); s3 += __shfl_xor(s3, 32);
      if ((tid & 48) == 0) {
        gs1[ 0 + j16][tb] = s0 + bs[0];
        gs1[16 + j16][tb] = s1 + bs[1];
        gs1[32 + j16][tb] = s2 + bs[2];
        gs1[48 + j16][tb] = s3 + bs[3];
      }
    }
    __syncthreads();   // C: gates ready

    // ---- wave0: layer0 pointwise + publish ----
    if (wv == 0 && t < TT) {
      float* h0n = (t & 1) ? h0b : h0a;
      #pragma unroll
      for (int u = 0; u < 4; ++u) {
        int c = ln + 64 * u;
        int pb = c >> 4, pj = c & 15;
        float gi = sigm(gs0[pj][pb]);
        float gf = sigm(gs0[16 + pj][pb]);
        float gg = tanhf(gs0[32 + pj][pb]);
        float go = sigm(gs0[48 + pj][pb]);
        c0r[u] = fmaf(gf, c0r[u], gi * gg);
        __hip_atomic_store(&h0n[(bg * 16 + pb) * HID + jc * 16 + pj],
                           go * tanhf(c0r[u]),
                           __ATOMIC_RELAXED, __HIP_MEMORY_SCOPE_AGENT);
      }
      asm volatile("s_waitcnt vmcnt(0)" ::: "memory");
      if (ln == 0)
        __hip_atomic_store(&flags0[(bg * 16 + jc) * 16], (u32)(t + 1),
                           __ATOMIC_RELAXED, __HIP_MEMORY_SCOPE_AGENT);
    }

    // ---- wave1: layer1 pointwise + publish (step t-2) ----
    if (wv == 1 && t >= 2) {
      float* h1n = (t & 1) ? h1b : h1a;   // parity of s = t-2
      #pragma unroll
      for (int u = 0; u < 4; ++u) {
        int c = ln + 64 * u;
        int pb = c >> 4, pj = c & 15;
        float gi = sigm(gs1[pj][pb]);
        float gf = sigm(gs1[16 + pj][pb]);
        float gg = tanhf(gs1[32 + pj][pb]);
        float go = sigm(gs1[48 + pj][pb]);
        c1r[u] = fmaf(gf, c1r[u], gi * gg);
        __hip_atomic_store(&h1n[(bg * 16 + pb) * HID + jc * 16 + pj],
                           go * tanhf(c1r[u]),
                           __ATOMIC_RELAXED, __HIP_MEMORY_SCOPE_AGENT);
      }
      asm volatile("s_waitcnt vmcnt(0)" ::: "memory");
      if (ln == 0)
        __hip_atomic_store(&flags1[(bg * 16 + jc) * 16], (u32)(t - 1),
                           __ATOMIC_RELAXED, __HIP_MEMORY_SCOPE_AGENT);
    }
  }
}

// MLP head: out[b] = fc2_w . relu(fc1_w @ h[b] + fc1_b) + fc2_b
__global__ __launch_bounds__(128) void k_fc(
    const float* __restrict__ hfin,
    const void* __restrict__ fc1w, const void* __restrict__ fc1b,
    const void* __restrict__ fc2w, const void* __restrict__ fc2b,
    const int* __restrict__ flag, void* __restrict__ out) {
  int b = blockIdx.x, j = threadIdx.x;  // 128 threads
  __shared__ float red[128];
  const float* h = hfin + b * HID;
  int isbf = flag[0];
  float acc = isbf ? bf1(((const u16*)fc1b)[j]) : ((const float*)fc1b)[j];
  if (isbf) {
    const u16* w = (const u16*)fc1w + j * HID;
    for (int k = 0; k < HID; k++) acc = fmaf(bf1(w[k]), h[k], acc);
  } else {
    const float* w = (const float*)fc1w + j * HID;
    for (int k = 0; k < HID; k++) acc = fmaf(w[k], h[k], acc);
  }
  acc = fmaxf(acc, 0.f);
  float w2 = isbf ? bf1(((const u16*)fc2w)[j]) : ((const float*)fc2w)[j];
  red[j] = acc * w2;
  __syncthreads();
  for (int s = 64; s > 0; s >>= 1) {
    if (j < s) red[j] += red[j + s];
    __syncthreads();
  }
  if (j == 0) {
    float b2 = isbf ? bf1(((const u16*)fc2b)[0]) : ((const float*)fc2b)[0];
    float r = red[0] + b2;
    if (isbf) ((u16*)out)[b] = f2bf(r);
    else      ((float*)out)[b] = r;
  }
}

extern "C" void kernel_launch(void* const* d_in, const int* in_sizes, int n_in,
                              void* d_out, int out_size, void* d_ws, size_t ws_size,
                              hipStream_t stream) {
  const int* ids   = (const int*)d_in[0];
  const void* emb  = d_in[1];
  const void* wih0 = d_in[2];
  const void* whh0 = d_in[3];
  const void* bih0 = d_in[4];
  const void* bhh0 = d_in[5];
  const void* wih1 = d_in[6];
  const void* whh1 = d_in[7];
  const void* bih1 = d_in[8];
  const void* bhh1 = d_in[9];
  const void* fc1w = d_in[10];
  const void* fc1b = d_in[11];
  const void* fc2w = d_in[12];
  const void* fc2b = d_in[13];

  float* ws = (float*)d_ws;
  int*   flag    = (int*)ws;                  // 16-float pad
  float* W0emb   = ws + 16;                   // 27648
  float* whh0_f  = W0emb  + VOC * GATES;      // 262144
  float* wih1_f  = whh0_f + GATES * HID;      // 262144
  float* whh1_f  = wih1_f + GATES * HID;      // 262144
  float* bih1_f  = whh1_f + GATES * HID;      // 1024
  float* bhh1_f  = bih1_f + GATES;            // 1024
  float* h0A = bhh1_f + GATES;                // 65536 each below
  float* h0B = h0A + BATCH * HID;
  float* c0  = h0B + BATCH * HID;             // reused as flag arrays
  float* h1A = c0  + BATCH * HID;
  float* h1B = h1A + BATCH * HID;
  float* c1  = h1B + BATCH * HID;
  u32*   bar = (u32*)c0;                      // flags0[256*16], flags1[256*16]

  k_detect<<<1, 64, 0, stream>>>((const u16*)bih0, flag);

  k_convert<<<(GATES * HID + 255) / 256, 256, 0, stream>>>(whh0, whh0_f, GATES * HID, flag);
  k_convert<<<(GATES * HID + 255) / 256, 256, 0, stream>>>(wih1, wih1_f, GATES * HID, flag);
  k_convert<<<(GATES * HID + 255) / 256, 256, 0, stream>>>(whh1, whh1_f, GATES * HID, flag);
  k_convert<<<(GATES + 255) / 256, 256, 0, stream>>>(bih1, bih1_f, GATES, flag);
  k_convert<<<(GATES + 255) / 256, 256, 0, stream>>>(bhh1, bhh1_f, GATES, flag);

  // zero h0A,h0B,c0(=flags),h1A,h1B,c1 — also resets flags each replay
  hipMemsetAsync(h0A, 0, (size_t)6 * BATCH * HID * sizeof(float), stream);

  k_prep<<<(VOC * GATES + 255) / 256, 256, 0, stream>>>(emb, wih0, bih0, bhh0, flag, W0emb);

  k_lstm<<<256, 1024, 0, stream>>>(ids, W0emb, whh0_f, wih1_f, whh1_f,
                                   bih1_f, bhh1_f, h0A, h0B, h1A, h1B, bar);

  // L1 step 511 computed at iter t=513 -> stored into h1B (511 odd)
  k_fc<<<BATCH, 128, 0, stream>>>(h1B, fc1w, fc1b, fc2w, fc2b, flag, d_out);
}

// Round 8
// 13099.429 us; speedup vs baseline: 1.2667x; 1.2667x over previous
//
#include <hip/hip_runtime.h>

typedef unsigned short u16;
typedef unsigned int u32;
typedef unsigned long long u64;
typedef float f32x2 __attribute__((ext_vector_type(2)));

#define BATCH 256
#define TT 512
#define HID 256
#define GATES 1024   // 4*HID
#define NEMB 512
#define VOC 27
#define HPAD 260     // 1040B row: 16B aligned, 2-way LDS conflict max (free)

__device__ __forceinline__ float bf1(u16 x){ union{u32 u; float f;} v; v.u = ((u32)x) << 16; return v.f; }
__device__ __forceinline__ u16 f2bf(float f){
  union{float f; u32 u;} v; v.f = f;
  u32 u = v.u;
  return (u16)((u + 0x7fffu + ((u >> 16) & 1u)) >> 16);
}
__device__ __forceinline__ float sigm(float x){ return 1.f / (1.f + __expf(-x)); }
__device__ __forceinline__ f32x2 lo2(float4 v){ f32x2 r; r.x = v.x; r.y = v.y; return r; }
__device__ __forceinline__ f32x2 hi2(float4 v){ f32x2 r; r.x = v.z; r.y = v.w; return r; }

// Sniff storage dtype of b_ih0 (1024 elems, |v| <= 1/16).
__global__ void k_detect(const u16* __restrict__ b, int* __restrict__ flag) {
  int bad = 0;
  for (int k = threadIdx.x; k < 512; k += 64)
    if (((b[2 * k] >> 7) & 0xFF) >= 127) bad = 1;
  unsigned long long m = __ballot(bad);   // single wave
  if (threadIdx.x == 0) flag[0] = (m != 0ULL) ? 0 : 1;
}

__global__ void k_convert(const void* __restrict__ src, float* __restrict__ dst,
                          int n, const int* __restrict__ flag) {
  int i = blockIdx.x * 256 + threadIdx.x;
  if (i >= n) return;
  dst[i] = flag[0] ? bf1(((const u16*)src)[i]) : ((const float*)src)[i];
}

// W0emb[v][g] = sum_i emb[v][i]*w_ih0[g][i] + b_ih0[g] + b_hh0[g]; emb row 26 := 0
__global__ void k_prep(const void* __restrict__ emb, const void* __restrict__ wih,
                       const void* __restrict__ bih, const void* __restrict__ bhh,
                       const int* __restrict__ flag, float* __restrict__ W0) {
  int idx = blockIdx.x * 256 + threadIdx.x;
  if (idx >= VOC * GATES) return;
  int v = idx >> 10, g = idx & (GATES - 1);
  int isbf = flag[0];
  float acc = isbf ? (bf1(((const u16*)bih)[g]) + bf1(((const u16*)bhh)[g]))
                   : (((const float*)bih)[g] + ((const float*)bhh)[g]);
  if (v != 26) {
    float s = 0.f;
    if (isbf) {
      const u16* e = (const u16*)emb + v * NEMB;
      const u16* w = (const u16*)wih + g * NEMB;
      for (int i = 0; i < NEMB; i++) s = fmaf(bf1(e[i]), bf1(w[i]), s);
    } else {
      const float* e = (const float*)emb + v * NEMB;
      const float* w = (const float*)wih + g * NEMB;
      for (int i = 0; i < NEMB; i++) s = fmaf(e[i], w[i], s);
    }
    acc += s;
  }
  W0[idx] = acc;
}

// Persistent fused 2-layer LSTM, software-pipelined exchange.
// 256 blocks x 1024 threads, 1 block/CU. Block (bg,jc): 16 batches x 16 j.
// *** R8 change (only change vs R4): bid->(bg,jc) remap for L2 weight residency.
// Under round-robin dispatch XCD x hosts bids == x (mod 8). Mapping
//   jc = (bid&7)*2 + (bid>>7),  bg = (bid>>3)&15
// gives each XCD's 32 resident blocks only TWO jc values -> per-XCD weight
// working set = 2 x 192KB = 384KB (was 16 x 192KB = 6MB > 4MB L2, thrashing
// to L3 every iteration at ~600-900cy exposed latency). Weights now stay
// L2-resident across all 512 iterations. Group membership spans XCDs, which
// the proven sc1 exchange protocol (R2-R4) already handles.
// Skew: iter t computes L0 step t and L1 step t-2.
//   cnt0 publishes h0[t] BEFORE the L1 gemm -> barrier round trip overlaps L1 work.
//   cnt1 publishes h1[t-2]; consumers need it one full iteration later (slack).
// Coherence: relaxed AGENT atomics only (no wbl2/inv); __syncthreads drains
// vmcnt(0) before each arrive, so stores are at the coherence point.
__global__ __launch_bounds__(1024) void k_lstm(
    const int* __restrict__ ids, const float* __restrict__ W0,
    const float* __restrict__ whh0, const float* __restrict__ wih1,
    const float* __restrict__ whh1,
    const float* __restrict__ bih1, const float* __restrict__ bhh1,
    float* __restrict__ h0a, float* __restrict__ h0b,
    float* __restrict__ h1a, float* __restrict__ h1b,
    u32* __restrict__ bar)
{
  const int tid = threadIdx.x;
  const int bid = blockIdx.x;
  const int bg = (bid >> 3) & 15;            // [0,16) batch group
  const int jc = (bid & 7) * 2 + (bid >> 7); // [0,16) j-chunk; 2 per XCD

  const int tb = tid & 15;            // batch-in-group for GEMM phase
  const int rr = tid >> 4;            // row slot [0,64): gate = rr>>4, joff = rr&15
  const int grow = ((rr >> 4) << 8) + (jc << 4) + (rr & 15);

  __shared__ __align__(16) float hp0[2][16][HPAD]; // h0[t-1]/h0[t-2] tiles (double buf)
  __shared__ __align__(16) float hp1[16][HPAD];    // h1[t-3] tile
  __shared__ float gs0[64][17];       // layer0 gates [row][b], pad 17
  __shared__ float gs1[64][17];       // layer1 gates
  __shared__ int   ids_l[16][TT + 1]; // all ids for this bg, pad 513

  const float* wl0 = whh0 + (size_t)grow * HID;
  const float* wi  = wih1 + (size_t)grow * HID;
  const float* wh  = whh1 + (size_t)grow * HID;
  const float bsum = bih1[grow] + bhh1[grow];

  // pointwise role (tid < 256): cell (pb, pj); both layers' c-state in registers
  const int pj = tid & 15, pb = (tid >> 4) & 15;
  const int prow = (bg * 16 + pb) * HID + (jc * 16 + pj);
  float c0r = 0.f, c1r = 0.f;

  u32* cnt0 = bar + bg * 64;          // 256B-separated counter pairs
  u32* cnt1 = cnt0 + 32;

  // preload all ids for this batch group (coalesced, once)
  #pragma unroll
  for (int u = 0; u < 8; ++u) {
    int e = tid + 1024 * u;           // [0, 8192)
    int b = e >> 9, tt = e & 511;
    ids_l[b][tt] = ids[(bg * 16 + b) * TT + tt];
  }

  for (int t = 0; t <= TT + 1; ++t) {
    // ---- wait for group (tid0 spins; cnt1 has a full iter of slack) ----
    if (tid == 0) {
      if (t >= 1 && t <= TT) {
        u32 want = 16u * (u32)t;
        while (__hip_atomic_load(cnt0, __ATOMIC_RELAXED, __HIP_MEMORY_SCOPE_AGENT) < want)
          __builtin_amdgcn_s_sleep(1);
      }
      if (t >= 3) {
        u32 want = 16u * (u32)(t - 2);
        while (__hip_atomic_load(cnt1, __ATOMIC_RELAXED, __HIP_MEMORY_SCOPE_AGENT) < want)
          __builtin_amdgcn_s_sleep(1);
      }
    }
    __syncthreads();

    // ---- stage tiles (relaxed agent loads; coalesced; 2-way LDS banks) ----
    if (t <= TT) {
      const float* h0p = ((t + 1) & 1) ? h0b : h0a;      // h0[t-1]
      const u64* s0 = (const u64*)(h0p + bg * 16 * HID);
      float (*dst)[HPAD] = hp0[t & 1];
      #pragma unroll
      for (int u = 0; u < 2; ++u) {
        int e = tid + 1024 * u;
        u64 v = __hip_atomic_load(s0 + e, __ATOMIC_RELAXED, __HIP_MEMORY_SCOPE_AGENT);
        *(u64*)&dst[e >> 7][(e & 127) * 2] = v;
      }
    }
    if (t >= 2) {
      const float* h1p = ((t + 1) & 1) ? h1b : h1a;      // h1[t-3]
      const u64* s1 = (const u64*)(h1p + bg * 16 * HID);
      #pragma unroll
      for (int u = 0; u < 2; ++u) {
        int e = tid + 1024 * u;
        u64 v = __hip_atomic_load(s1 + e, __ATOMIC_RELAXED, __HIP_MEMORY_SCOPE_AGENT);
        *(u64*)&hp1[e >> 7][(e & 127) * 2] = v;
      }
    }
    __syncthreads();

    // ---- layer0 gates, step t (packed f32 -> v_pk_fma_f32) ----
    if (t < TT) {
      float xgv = W0[(size_t)ids_l[tb][t] * GATES + grow];
      const float4* w4 = (const float4*)wl0;
      const float4* h4 = (const float4*)hp0[t & 1][tb];
      f32x2 sA = {0.f, 0.f}, sB = {0.f, 0.f};
      #pragma unroll 8
      for (int k = 0; k < 64; ++k) {
        float4 q = w4[k], hv = h4[k];
        sA = lo2(q) * lo2(hv) + sA;
        sB = hi2(q) * hi2(hv) + sB;
      }
      gs0[rr][tb] = xgv + sA.x + sA.y + sB.x + sB.y;
    }
    __syncthreads();

    // ---- layer0 pointwise: store h0[t], then PUBLISH (overlaps with L1 below) ----
    if (t < TT && tid < 256) {
      float gi = sigm(gs0[pj][pb]);
      float gf = sigm(gs0[16 + pj][pb]);
      float gg = tanhf(gs0[32 + pj][pb]);
      float go = sigm(gs0[48 + pj][pb]);
      c0r = fmaf(gf, c0r, gi * gg);
      float* h0n = (t & 1) ? h0b : h0a;
      __hip_atomic_store(&h0n[prow], go * tanhf(c0r),
                         __ATOMIC_RELAXED, __HIP_MEMORY_SCOPE_AGENT);
    }
    __syncthreads();   // drains vmcnt(0): h0 stores at coherence point
    if (tid == 0 && t < TT)
      __hip_atomic_fetch_add(cnt0, 1u, __ATOMIC_RELAXED, __HIP_MEMORY_SCOPE_AGENT);

    // ---- layer1 gates, step t-2 (uses hp0 prev buffer + hp1; overlaps barrier) ----
    if (t >= 2) {
      const float4* wi4 = (const float4*)wi;
      const float4* wh4 = (const float4*)wh;
      const float4* x4  = (const float4*)hp0[(t - 1) & 1][tb];
      const float4* h4  = (const float4*)hp1[tb];
      f32x2 sIa = {0.f,0.f}, sIb = {0.f,0.f}, sHa = {0.f,0.f}, sHb = {0.f,0.f};
      #pragma unroll 8
      for (int k = 0; k < 64; ++k) {
        float4 qi = wi4[k], qh = wh4[k], xv = x4[k], hv = h4[k];
        sIa = lo2(qi) * lo2(xv) + sIa;
        sIb = hi2(qi) * hi2(xv) + sIb;
        sHa = lo2(qh) * lo2(hv) + sHa;
        sHb = hi2(qh) * hi2(hv) + sHb;
      }
      gs1[rr][tb] = bsum + sIa.x + sIa.y + sIb.x + sIb.y
                         + sHa.x + sHa.y + sHb.x + sHb.y;
    }
    __syncthreads();

    // ---- layer1 pointwise: store h1[t-2], publish cnt1 ----
    if (t >= 2 && tid < 256) {
      float gi = sigm(gs1[pj][pb]);
      float gf = sigm(gs1[16 + pj][pb]);
      float gg = tanhf(gs1[32 + pj][pb]);
      float go = sigm(gs1[48 + pj][pb]);
      c1r = fmaf(gf, c1r, gi * gg);
      float* h1n = (t & 1) ? h1b : h1a;   // parity of s = t-2
      __hip_atomic_store(&h1n[prow], go * tanhf(c1r),
                         __ATOMIC_RELAXED, __HIP_MEMORY_SCOPE_AGENT);
    }
    __syncthreads();   // drains vmcnt(0): h1 stores at coherence point
    if (tid == 0 && t >= 2 && t <= TT)
      __hip_atomic_fetch_add(cnt1, 1u, __ATOMIC_RELAXED, __HIP_MEMORY_SCOPE_AGENT);
  }
}

// MLP head: out[b] = fc2_w . relu(fc1_w @ h[b] + fc1_b) + fc2_b
__global__ __launch_bounds__(128) void k_fc(
    const float* __restrict__ hfin,
    const void* __restrict__ fc1w, const void* __restrict__ fc1b,
    const void* __restrict__ fc2w, const void* __restrict__ fc2b,
    const int* __restrict__ flag, void* __restrict__ out) {
  int b = blockIdx.x, j = threadIdx.x;  // 128 threads
  __shared__ float red[128];
  const float* h = hfin + b * HID;
  int isbf = flag[0];
  float acc = isbf ? bf1(((const u16*)fc1b)[j]) : ((const float*)fc1b)[j];
  if (isbf) {
    const u16* w = (const u16*)fc1w + j * HID;
    for (int k = 0; k < HID; k++) acc = fmaf(bf1(w[k]), h[k], acc);
  } else {
    const float* w = (const float*)fc1w + j * HID;
    for (int k = 0; k < HID; k++) acc = fmaf(w[k], h[k], acc);
  }
  acc = fmaxf(acc, 0.f);
  float w2 = isbf ? bf1(((const u16*)fc2w)[j]) : ((const float*)fc2w)[j];
  red[j] = acc * w2;
  __syncthreads();
  for (int s = 64; s > 0; s >>= 1) {
    if (j < s) red[j] += red[j + s];
    __syncthreads();
  }
  if (j == 0) {
    float b2 = isbf ? bf1(((const u16*)fc2b)[0]) : ((const float*)fc2b)[0];
    float r = red[0] + b2;
    if (isbf) ((u16*)out)[b] = f2bf(r);
    else      ((float*)out)[b] = r;
  }
}

extern "C" void kernel_launch(void* const* d_in, const int* in_sizes, int n_in,
                              void* d_out, int out_size, void* d_ws, size_t ws_size,
                              hipStream_t stream) {
  const int* ids   = (const int*)d_in[0];
  const void* emb  = d_in[1];
  const void* wih0 = d_in[2];
  const void* whh0 = d_in[3];
  const void* bih0 = d_in[4];
  const void* bhh0 = d_in[5];
  const void* wih1 = d_in[6];
  const void* whh1 = d_in[7];
  const void* bih1 = d_in[8];
  const void* bhh1 = d_in[9];
  const void* fc1w = d_in[10];
  const void* fc1b = d_in[11];
  const void* fc2w = d_in[12];
  const void* fc2b = d_in[13];

  float* ws = (float*)d_ws;
  int*   flag    = (int*)ws;                  // 16-float pad
  float* W0emb   = ws + 16;                   // 27648
  float* whh0_f  = W0emb  + VOC * GATES;      // 262144
  float* wih1_f  = whh0_f + GATES * HID;      // 262144
  float* whh1_f  = wih1_f + GATES * HID;      // 262144
  float* bih1_f  = whh1_f + GATES * HID;      // 1024
  float* bhh1_f  = bih1_f + GATES;            // 1024
  float* h0A = bhh1_f + GATES;                // 65536 each below
  float* h0B = h0A + BATCH * HID;
  float* c0  = h0B + BATCH * HID;             // reused as barrier counters
  float* h1A = c0  + BATCH * HID;
  float* h1B = h1A + BATCH * HID;
  float* c1  = h1B + BATCH * HID;
  u32*   bar = (u32*)c0;                      // 16 groups x (cnt0,cnt1) pairs, 256B apart

  k_detect<<<1, 64, 0, stream>>>((const u16*)bih0, flag);

  k_convert<<<(GATES * HID + 255) / 256, 256, 0, stream>>>(whh0, whh0_f, GATES * HID, flag);
  k_convert<<<(GATES * HID + 255) / 256, 256, 0, stream>>>(wih1, wih1_f, GATES * HID, flag);
  k_convert<<<(GATES * HID + 255) / 256, 256, 0, stream>>>(whh1, whh1_f, GATES * HID, flag);
  k_convert<<<(GATES + 255) / 256, 256, 0, stream>>>(bih1, bih1_f, GATES, flag);
  k_convert<<<(GATES + 255) / 256, 256, 0, stream>>>(bhh1, bhh1_f, GATES, flag);

  // zero h0A,h0B,c0(=bar),h1A,h1B,c1 — also resets barrier counters each replay
  hipMemsetAsync(h0A, 0, (size_t)6 * BATCH * HID * sizeof(float), stream);

  k_prep<<<(VOC * GATES + 255) / 256, 256, 0, stream>>>(emb, wih0, bih0, bhh0, flag, W0emb);

  k_lstm<<<256, 1024, 0, stream>>>(ids, W0emb, whh0_f, wih1_f, whh1_f,
                                   bih1_f, bhh1_f, h0A, h0B, h1A, h1B, bar);

  // L1 step 511 computed at iter t=513 (odd) -> stored into h1B
  k_fc<<<BATCH, 128, 0, stream>>>(h1B, fc1w, fc1b, fc2w, fc2b, flag, d_out);
}

// Round 9
// 12441.631 us; speedup vs baseline: 1.3337x; 1.0529x over previous
//
#include <hip/hip_runtime.h>

typedef unsigned short u16;
typedef unsigned int u32;
typedef unsigned long long u64;
typedef float f32x2 __attribute__((ext_vector_type(2)));

#define BATCH 256
#define TT 512
#define HID 256
#define GATES 1024   // 4*HID
#define NEMB 512
#define VOC 27
#define HPAD 260     // 1040B row: 16B aligned, 2-way LDS conflict max (free)

__device__ __forceinline__ float bf1(u16 x){ union{u32 u; float f;} v; v.u = ((u32)x) << 16; return v.f; }
__device__ __forceinline__ u16 f2bf(float f){
  union{float f; u32 u;} v; v.f = f;
  u32 u = v.u;
  return (u16)((u + 0x7fffu + ((u >> 16) & 1u)) >> 16);
}
__device__ __forceinline__ float sigm(float x){ return 1.f / (1.f + __expf(-x)); }
__device__ __forceinline__ f32x2 lo2(float4 v){ f32x2 r; r.x = v.x; r.y = v.y; return r; }
__device__ __forceinline__ f32x2 hi2(float4 v){ f32x2 r; r.x = v.z; r.y = v.w; return r; }

// Sniff storage dtype of b_ih0 (1024 elems, |v| <= 1/16).
__global__ void k_detect(const u16* __restrict__ b, int* __restrict__ flag) {
  int bad = 0;
  for (int k = threadIdx.x; k < 512; k += 64)
    if (((b[2 * k] >> 7) & 0xFF) >= 127) bad = 1;
  unsigned long long m = __ballot(bad);   // single wave
  if (threadIdx.x == 0) flag[0] = (m != 0ULL) ? 0 : 1;
}

__global__ void k_convert(const void* __restrict__ src, float* __restrict__ dst,
                          int n, const int* __restrict__ flag) {
  int i = blockIdx.x * 256 + threadIdx.x;
  if (i >= n) return;
  dst[i] = flag[0] ? bf1(((const u16*)src)[i]) : ((const float*)src)[i];
}

// W0emb[v][g] = sum_i emb[v][i]*w_ih0[g][i] + b_ih0[g] + b_hh0[g]; emb row 26 := 0
__global__ void k_prep(const void* __restrict__ emb, const void* __restrict__ wih,
                       const void* __restrict__ bih, const void* __restrict__ bhh,
                       const int* __restrict__ flag, float* __restrict__ W0) {
  int idx = blockIdx.x * 256 + threadIdx.x;
  if (idx >= VOC * GATES) return;
  int v = idx >> 10, g = idx & (GATES - 1);
  int isbf = flag[0];
  float acc = isbf ? (bf1(((const u16*)bih)[g]) + bf1(((const u16*)bhh)[g]))
                   : (((const float*)bih)[g] + ((const float*)bhh)[g]);
  if (v != 26) {
    float s = 0.f;
    if (isbf) {
      const u16* e = (const u16*)emb + v * NEMB;
      const u16* w = (const u16*)wih + g * NEMB;
      for (int i = 0; i < NEMB; i++) s = fmaf(bf1(e[i]), bf1(w[i]), s);
    } else {
      const float* e = (const float*)emb + v * NEMB;
      const float* w = (const float*)wih + g * NEMB;
      for (int i = 0; i < NEMB; i++) s = fmaf(e[i], w[i], s);
    }
    acc += s;
  }
  W0[idx] = acc;
}

// Persistent fused 2-layer LSTM, 256 blocks x 1024 threads, 1 block/CU.
// *** R9: sync-group shrunk 16 -> 4 blocks (the one parameter never varied;
// every within-iteration optimization R2-R8 left the 25.5us period flat).
// 64 groups x 4 blocks; group g owns batches [4g,4g+4); block owns a QUARTER
// of j (64 j = 256 gate rows per matrix). Per-block compute unchanged
// (786K FMA/iter); weight streaming/block 192->768 KB/iter from L2 (total
// weights 3MB < 4MB L2, always resident). Exchange: 3 peers (not 15),
// single-writer 64B-spaced flag slots (no RMW), 6 poll lanes at sleep(2).
// group = (bid>>3)*2 + (bid&1); jq = (bid&7)>>1  -> members of a group are
// bids {base, base+2, base+4, base+6} (same parity), and under round-robin
// each XCD hosts a single jq (768 KB slice, trivially L2-resident).
// Skew (copied R4/R8): iter t computes L0 step t and L1 step t-2; flags0
// published BEFORE L1 gemm (overlap); flags1 has a full iteration of slack.
// Coherence: relaxed AGENT atomics only; __syncthreads drains vmcnt(0)
// before each publish (protocol proven R2-R8).
__global__ __launch_bounds__(1024) void k_lstm(
    const int* __restrict__ ids, const float* __restrict__ W0,
    const float* __restrict__ whh0, const float* __restrict__ wih1,
    const float* __restrict__ whh1,
    const float* __restrict__ bih1, const float* __restrict__ bhh1,
    float* __restrict__ h0a, float* __restrict__ h0b,
    float* __restrict__ h1a, float* __restrict__ h1b,
    u32* __restrict__ bar)
{
  const int tid = threadIdx.x;
  const int bid = blockIdx.x;
  const int grp = ((bid >> 3) << 1) | (bid & 1);  // [0,64) batch group (4 batches)
  const int jq  = (bid & 7) >> 1;                 // [0,4) j-quarter (64 j)
  const int wv  = tid >> 6;
  const int ln  = tid & 63;

  const int tb = tid & 3;             // batch within group for GEMM phase
  const int rr = tid >> 2;            // row slot [0,256): gate = rr>>6, j = rr&63
  const int grow = (rr >> 6) * 256 + jq * 64 + (rr & 63);

  __shared__ __align__(16) float hp0[2][4][HPAD]; // h0[t-1]/h0[t-2] tiles
  __shared__ __align__(16) float hp1[4][HPAD];    // h1[t-3] tile
  __shared__ float gs0[256][5];       // layer0 gates [gate*64+j][tb]
  __shared__ float gs1[256][5];       // layer1 gates
  __shared__ int   ids_l[4][TT];      // all ids for this group's 4 batches

  const float* wl0 = whh0 + (size_t)grow * HID;
  const float* wi  = wih1 + (size_t)grow * HID;
  const float* wh  = whh1 + (size_t)grow * HID;
  const float bsum = bih1[grow] + bhh1[grow];

  // pointwise role (tid < 256): cell (pb, pj); both layers' c-state in registers
  const int pb = tid & 3, pj = (tid >> 2) & 63;
  const int prow = (grp * 4 + pb) * HID + (jq * 64 + pj);
  float c0r = 0.f, c1r = 0.f;

  u32* flags0 = bar;                  // slot bid*16 (64B apart), single-writer
  u32* flags1 = bar + 4096;

  // preload all ids for this group's 4 batches (coalesced, once)
  #pragma unroll
  for (int u = 0; u < 2; ++u) {
    int e = tid + 1024 * u;           // [0, 2048)
    int b = e >> 9, tt = e & 511;
    ids_l[b][tt] = ids[(grp * 4 + b) * TT + tt];
  }

  for (int t = 0; t <= TT + 1; ++t) {
    // ---- wave0: poll 3 peers' flags (single-writer slots, no RMW) ----
    if (wv == 0) {
      const int q = ln & 3;
      const int pbid = ((bid >> 3) << 3) | (q << 1) | (bid & 1);
      u32 need = 0;
      const u32* fp = nullptr;
      if (ln < 4) {
        if (q != jq && t >= 1 && t <= TT) { fp = flags0 + pbid * 16; need = (u32)t; }
      } else if (ln < 8) {
        if (q != jq && t >= 3) { fp = flags1 + pbid * 16; need = (u32)(t - 2); }
      }
      for (;;) {
        bool ok = true;
        if (need) ok = __hip_atomic_load(fp, __ATOMIC_RELAXED, __HIP_MEMORY_SCOPE_AGENT) >= need;
        if (__all(ok)) break;
        __builtin_amdgcn_s_sleep(2);
      }
    }
    __syncthreads();   // A: flags ok + prev-iter gemm done reading hp tiles

    // ---- stage tiles (relaxed agent loads; 4KB each; coalesced) ----
    if (tid < 512) {
      if (t <= TT) {
        const float* h0p = ((t + 1) & 1) ? h0b : h0a;    // h0[t-1]
        const u64* s0 = (const u64*)h0p;
        int e = tid;                                     // [0,512) u64
        u64 v = __hip_atomic_load(s0 + grp * 512 + e, __ATOMIC_RELAXED, __HIP_MEMORY_SCOPE_AGENT);
        *(u64*)&hp0[t & 1][e >> 7][(e & 127) * 2] = v;
      }
    } else {
      if (t >= 2) {
        const float* h1p = ((t + 1) & 1) ? h1b : h1a;    // h1[t-3]
        const u64* s1 = (const u64*)h1p;
        int e = tid - 512;
        u64 v = __hip_atomic_load(s1 + grp * 512 + e, __ATOMIC_RELAXED, __HIP_MEMORY_SCOPE_AGENT);
        *(u64*)&hp1[e >> 7][(e & 127) * 2] = v;
      }
    }
    __syncthreads();   // B: tiles staged

    // ---- layer0 gates, step t: one (row,batch) per thread (packed f32) ----
    if (t < TT) {
      float xgv = W0[(size_t)ids_l[tb][t] * GATES + grow];
      const float4* w4 = (const float4*)wl0;
      const float4* h4 = (const float4*)hp0[t & 1][tb];
      f32x2 sA = {0.f, 0.f}, sB = {0.f, 0.f};
      #pragma unroll 8
      for (int k = 0; k < 64; ++k) {
        float4 q = w4[k], hv = h4[k];
        sA = lo2(q) * lo2(hv) + sA;
        sB = hi2(q) * hi2(hv) + sB;
      }
      gs0[rr][tb] = xgv + sA.x + sA.y + sB.x + sB.y;
    }
    __syncthreads();   // C: layer0 gates ready

    // ---- layer0 pointwise: store h0[t], then PUBLISH (overlaps with L1) ----
    if (t < TT && tid < 256) {
      float gi = sigm(gs0[pj][pb]);
      float gf = sigm(gs0[64 + pj][pb]);
      float gg = tanhf(gs0[128 + pj][pb]);
      float go = sigm(gs0[192 + pj][pb]);
      c0r = fmaf(gf, c0r, gi * gg);
      float* h0n = (t & 1) ? h0b : h0a;
      __hip_atomic_store(&h0n[prow], go * tanhf(c0r),
                         __ATOMIC_RELAXED, __HIP_MEMORY_SCOPE_AGENT);
    }
    __syncthreads();   // D: drains vmcnt(0) -> h0 stores at coherence point
    if (tid == 0 && t < TT)
      __hip_atomic_store(flags0 + bid * 16, (u32)(t + 1),
                         __ATOMIC_RELAXED, __HIP_MEMORY_SCOPE_AGENT);

    // ---- layer1 gates, step t-2 (x = hp0 prev buffer, h = hp1) ----
    if (t >= 2) {
      const float4* wi4 = (const float4*)wi;
      const float4* wh4 = (const float4*)wh;
      const float4* x4  = (const float4*)hp0[(t - 1) & 1][tb];
      const float4* h4  = (const float4*)hp1[tb];
      f32x2 sIa = {0.f,0.f}, sIb = {0.f,0.f}, sHa = {0.f,0.f}, sHb = {0.f,0.f};
      #pragma unroll 8
      for (int k = 0; k < 64; ++k) {
        float4 qi = wi4[k], qh = wh4[k], xv = x4[k], hv = h4[k];
        sIa = lo2(qi) * lo2(xv) + sIa;
        sIb = hi2(qi) * hi2(xv) + sIb;
        sHa = lo2(qh) * lo2(hv) + sHa;
        sHb = hi2(qh) * hi2(hv) + sHb;
      }
      gs1[rr][tb] = bsum + sIa.x + sIa.y + sIb.x + sIb.y
                         + sHa.x + sHa.y + sHb.x + sHb.y;
    }
    __syncthreads();   // E: layer1 gates ready

    // ---- layer1 pointwise: store h1[t-2], publish flags1 ----
    if (t >= 2 && tid < 256) {
      float gi = sigm(gs1[pj][pb]);
      float gf = sigm(gs1[64 + pj][pb]);
      float gg = tanhf(gs1[128 + pj][pb]);
      float go = sigm(gs1[192 + pj][pb]);
      c1r = fmaf(gf, c1r, gi * gg);
      float* h1n = (t & 1) ? h1b : h1a;   // parity of s = t-2
      __hip_atomic_store(&h1n[prow], go * tanhf(c1r),
                         __ATOMIC_RELAXED, __HIP_MEMORY_SCOPE_AGENT);
    }
    __syncthreads();   // F: drains vmcnt(0) -> h1 stores at coherence point
    if (tid == 0 && t >= 2 && t <= TT)
      __hip_atomic_store(flags1 + bid * 16, (u32)(t - 1),
                         __ATOMIC_RELAXED, __HIP_MEMORY_SCOPE_AGENT);
  }
}

// MLP head: out[b] = fc2_w . relu(fc1_w @ h[b] + fc1_b) + fc2_b
__global__ __launch_bounds__(128) void k_fc(
    const float* __restrict__ hfin,
    const void* __restrict__ fc1w, const void* __restrict__ fc1b,
    const void* __restrict__ fc2w, const void* __restrict__ fc2b,
    const int* __restrict__ flag, void* __restrict__ out) {
  int b = blockIdx.x, j = threadIdx.x;  // 128 threads
  __shared__ float red[128];
  const float* h = hfin + b * HID;
  int isbf = flag[0];
  float acc = isbf ? bf1(((const u16*)fc1b)[j]) : ((const float*)fc1b)[j];
  if (isbf) {
    const u16* w = (const u16*)fc1w + j * HID;
    for (int k = 0; k < HID; k++) acc = fmaf(bf1(w[k]), h[k], acc);
  } else {
    const float* w = (const float*)fc1w + j * HID;
    for (int k = 0; k < HID; k++) acc = fmaf(w[k], h[k], acc);
  }
  acc = fmaxf(acc, 0.f);
  float w2 = isbf ? bf1(((const u16*)fc2w)[j]) : ((const float*)fc2w)[j];
  red[j] = acc * w2;
  __syncthreads();
  for (int s = 64; s > 0; s >>= 1) {
    if (j < s) red[j] += red[j + s];
    __syncthreads();
  }
  if (j == 0) {
    float b2 = isbf ? bf1(((const u16*)fc2b)[0]) : ((const float*)fc2b)[0];
    float r = red[0] + b2;
    if (isbf) ((u16*)out)[b] = f2bf(r);
    else      ((float*)out)[b] = r;
  }
}

extern "C" void kernel_launch(void* const* d_in, const int* in_sizes, int n_in,
                              void* d_out, int out_size, void* d_ws, size_t ws_size,
                              hipStream_t stream) {
  const int* ids   = (const int*)d_in[0];
  const void* emb  = d_in[1];
  const void* wih0 = d_in[2];
  const void* whh0 = d_in[3];
  const void* bih0 = d_in[4];
  const void* bhh0 = d_in[5];
  const void* wih1 = d_in[6];
  const void* whh1 = d_in[7];
  const void* bih1 = d_in[8];
  const void* bhh1 = d_in[9];
  const void* fc1w = d_in[10];
  const void* fc1b = d_in[11];
  const void* fc2w = d_in[12];
  const void* fc2b = d_in[13];

  float* ws = (float*)d_ws;
  int*   flag    = (int*)ws;                  // 16-float pad
  float* W0emb   = ws + 16;                   // 27648
  float* whh0_f  = W0emb  + VOC * GATES;      // 262144
  float* wih1_f  = whh0_f + GATES * HID;      // 262144
  float* whh1_f  = wih1_f + GATES * HID;      // 262144
  float* bih1_f  = whh1_f + GATES * HID;      // 1024
  float* bhh1_f  = bih1_f + GATES;            // 1024
  float* h0A = bhh1_f + GATES;                // 65536 each below
  float* h0B = h0A + BATCH * HID;
  float* c0  = h0B + BATCH * HID;             // reused as flag arrays
  float* h1A = c0  + BATCH * HID;
  float* h1B = h1A + BATCH * HID;
  float* c1  = h1B + BATCH * HID;
  u32*   bar = (u32*)c0;                      // flags0[256*16], flags1[256*16]

  k_detect<<<1, 64, 0, stream>>>((const u16*)bih0, flag);

  k_convert<<<(GATES * HID + 255) / 256, 256, 0, stream>>>(whh0, whh0_f, GATES * HID, flag);
  k_convert<<<(GATES * HID + 255) / 256, 256, 0, stream>>>(wih1, wih1_f, GATES * HID, flag);
  k_convert<<<(GATES * HID + 255) / 256, 256, 0, stream>>>(whh1, whh1_f, GATES * HID, flag);
  k_convert<<<(GATES + 255) / 256, 256, 0, stream>>>(bih1, bih1_f, GATES, flag);
  k_convert<<<(GATES + 255) / 256, 256, 0, stream>>>(bhh1, bhh1_f, GATES, flag);

  // zero h0A,h0B,c0(=flags),h1A,h1B,c1 — also resets flags each replay
  hipMemsetAsync(h0A, 0, (size_t)6 * BATCH * HID * sizeof(float), stream);

  k_prep<<<(VOC * GATES + 255) / 256, 256, 0, stream>>>(emb, wih0, bih0, bhh0, flag, W0emb);

  k_lstm<<<256, 1024, 0, stream>>>(ids, W0emb, whh0_f, wih1_f, whh1_f,
                                   bih1_f, bhh1_f, h0A, h0B, h1A, h1B, bar);

  // L1 step 511 computed at iter t=513 (odd) -> stored into h1B
  k_fc<<<BATCH, 128, 0, stream>>>(h1B, fc1w, fc1b, fc2w, fc2b, flag, d_out);
}